// Round 8
// baseline (49.447 us; speedup 1.0000x reference)
//
#include <hip/hip_runtime.h>

// Problem constants (match reference)
#define BB 64
#define N_WAY 5
#define N_SHOT 5
#define QUERY 15
#define NUM_SLOT 8
#define DD 640
#define IMGS (N_WAY * QUERY)      // 75
#define NS (BB * N_WAY * N_SHOT)  // 1600 support rows
#define NROWS 6400                // total rows
#define ROWSZ (NUM_SLOT * DD)     // 5120 floats per row
#define F4_PER_SLOT 160           // 640/4
#define NELEM (BB * IMGS)         // 4800 loss elements
#define NGROUP (BB * N_WAY)       // 320 support groups
#define NTASK 150                 // 75 path1 + 75 path2 dot-tasks per batch

// ---------------- K1: single streaming pass over out_f ----------------
// rowmean[6400][8] (per-row slot means), proto_all[320][8][640] (shot-means,
// all slots), pn2_all[320][8] (||proto||^2, all slots).
__global__ __launch_bounds__(256) void k_pass1(const float* __restrict__ out_f,
                                               float* __restrict__ rowmean,
                                               float* __restrict__ proto_all,
                                               float* __restrict__ pn2_all) {
    int b = blockIdx.x;
    int t = threadIdx.x;
    int slot = t >> 5;            // 0..7
    int l = t & 31;
    if (b < NGROUP) {
        const int g = b;          // support group j*5+c
        float4 acc[5];
        #pragma unroll
        for (int k = 0; k < 5; ++k) acc[k] = make_float4(0.f, 0.f, 0.f, 0.f);
        #pragma unroll
        for (int sh = 0; sh < N_SHOT; ++sh) {
            const float4* p = (const float4*)(out_f +
                ((size_t)((g * N_SHOT + sh) * NUM_SLOT + slot)) * DD);
            float s = 0.f;
            #pragma unroll
            for (int k = 0; k < 5; ++k) {
                float4 v = p[l + k * 32];
                acc[k].x += v.x; acc[k].y += v.y; acc[k].z += v.z; acc[k].w += v.w;
                s += (v.x + v.y) + (v.z + v.w);
            }
            #pragma unroll
            for (int off = 16; off; off >>= 1) s += __shfl_down(s, off, 32);
            if (l == 0) rowmean[(g * N_SHOT + sh) * NUM_SLOT + slot] = s * (1.f / DD);
        }
        float4* pp = (float4*)(proto_all + ((size_t)(g * NUM_SLOT + slot)) * DD);
        float ssq = 0.f;
        #pragma unroll
        for (int k = 0; k < 5; ++k) {
            acc[k].x *= 0.2f; acc[k].y *= 0.2f; acc[k].z *= 0.2f; acc[k].w *= 0.2f;
            pp[l + k * 32] = acc[k];
            ssq += acc[k].x * acc[k].x + acc[k].y * acc[k].y
                 + acc[k].z * acc[k].z + acc[k].w * acc[k].w;
        }
        #pragma unroll
        for (int off = 16; off; off >>= 1) ssq += __shfl_down(ssq, off, 32);
        if (l == 0) pn2_all[g * NUM_SLOT + slot] = ssq;
    } else {
        int r = NS + (b - NGROUP);   // query row
        const float4* p = (const float4*)(out_f + (size_t)r * ROWSZ) + slot * F4_PER_SLOT;
        float s = 0.f;
        #pragma unroll
        for (int k = 0; k < 5; ++k) {
            float4 v = p[l + k * 32];
            s += (v.x + v.y) + (v.z + v.w);
        }
        #pragma unroll
        for (int off = 16; off; off >>= 1) s += __shfl_down(s, off, 32);
        if (l == 0) rowmean[r * NUM_SLOT + slot] = s * (1.f / DD);
    }
}

// ---------------- K2: fused per-batch select + scan + scores + loss ----------------
// One block per batch, 512 threads (8 waves). Protos held in REGISTERS
// (each lane owns floats [lane*10, lane*10+10) of all 5 selected protos).
// part[j] = float4(sum nll1, sum nll2, sum acc1, sum acc2) over the batch.
__global__ __launch_bounds__(512) void k_mega(const float* __restrict__ out_f,
                                              const float* __restrict__ rowmean,
                                              const float* __restrict__ proto_all,
                                              const float* __restrict__ pn2_all,
                                              const int* __restrict__ labels_query,
                                              float4* __restrict__ part) {
    int j = blockIdx.x;            // batch
    int t = threadIdx.x;           // 0..511
    int wave = t >> 6, lane = t & 63;

    __shared__ __align__(16) float qb[IMGS * NUM_SLOT];  // 600 f
    __shared__ float supm[N_WAY * NUM_SLOT];             // 40 f
    __shared__ int   msS[N_WAY];
    __shared__ float p2S[N_WAY];
    __shared__ int   kS[IMGS];                           // 75 i
    __shared__ float scS[NTASK * N_WAY];                 // 750 f
    __shared__ float4 redS[128];

    // stage query row-means (float4) + support slot-means
    const float* qbase = rowmean + (size_t)(NS + j * IMGS) * NUM_SLOT;
    if (t < 150) ((float4*)qb)[t] = ((const float4*)qbase)[t];
    if (t >= 256 && t < 256 + N_WAY * NUM_SLOT) {
        int idx = t - 256;
        int c = idx >> 3, s = idx & 7;
        const float* sb = rowmean + (size_t)j * (N_WAY * N_SHOT * NUM_SLOT)
                          + c * (N_SHOT * NUM_SLOT) + s;
        supm[idx] = (sb[0] + sb[8] + sb[16] + sb[24] + sb[32]) * 0.2f;
    }
    __syncthreads();

    // greedy cover select (serial, tiny; first-occurrence among untaken)
    if (t == 0) {
        unsigned taken = 0u;
        #pragma unroll
        for (int c = 0; c < N_WAY; ++c) {
            float best = -3.0e38f; int bi = 0;
            #pragma unroll
            for (int s = 0; s < NUM_SLOT; ++s) {
                float v = supm[c * NUM_SLOT + s];
                if (!((taken >> s) & 1u) && v > best) { best = v; bi = s; }
            }
            taken |= (1u << bi);
            msS[c] = bi;
        }
    }
    __syncthreads();

    // p2S (wave 7 lanes, doesn't collide with wave-0 scan)
    if (t >= 448 && t < 448 + N_WAY) {
        int n = t - 448;
        p2S[n] = pn2_all[(j * N_WAY + n) * NUM_SLOT + msS[n]];
    }

    // proto registers: pv[n][k] = selected proto n, float2 #(lane*5+k)
    float2 pv[N_WAY][5];
    #pragma unroll
    for (int n = 0; n < N_WAY; ++n) {
        const float2* pp = (const float2*)(proto_all +
            ((size_t)((j * N_WAY + n) * NUM_SLOT + msS[n])) * DD) + lane * 5;
        #pragma unroll
        for (int k = 0; k < 5; ++k) pv[n][k] = pp[k];
    }

    // wave 0: inclusive prefix argmax over flat (s, c) -> kS[75]
    if (wave == 0) {
        int ms0 = msS[0], ms1 = msS[1], ms2 = msS[2], ms3 = msS[3], ms4 = msS[4];
        float bv; int bi;
        {
            const float* q = &qb[lane * NUM_SLOT];
            bv = q[ms0]; bi = lane * N_WAY;
            float v;
            v = q[ms1]; if (v > bv) { bv = v; bi = lane * N_WAY + 1; }
            v = q[ms2]; if (v > bv) { bv = v; bi = lane * N_WAY + 2; }
            v = q[ms3]; if (v > bv) { bv = v; bi = lane * N_WAY + 3; }
            v = q[ms4]; if (v > bv) { bv = v; bi = lane * N_WAY + 4; }
        }
        #pragma unroll
        for (int off = 1; off < 64; off <<= 1) {
            float ov = __shfl_up(bv, off, 64);
            int   oi = __shfl_up(bi, off, 64);
            if (lane >= off && !(bv > ov)) { bv = ov; bi = oi; }
        }
        kS[lane] = bi;
        float tv = __shfl(bv, 63, 64);
        int   ti = __shfl(bi, 63, 64);
        float bv2 = -3.0e38f; int bi2 = 0;
        if (lane < IMGS - 64) {
            int s = 64 + lane;
            const float* q = &qb[s * NUM_SLOT];
            bv2 = q[ms0]; bi2 = s * N_WAY;
            float v;
            v = q[ms1]; if (v > bv2) { bv2 = v; bi2 = s * N_WAY + 1; }
            v = q[ms2]; if (v > bv2) { bv2 = v; bi2 = s * N_WAY + 2; }
            v = q[ms3]; if (v > bv2) { bv2 = v; bi2 = s * N_WAY + 3; }
            v = q[ms4]; if (v > bv2) { bv2 = v; bi2 = s * N_WAY + 4; }
        }
        #pragma unroll
        for (int off = 1; off < 16; off <<= 1) {
            float ov = __shfl_up(bv2, off, 64);
            int   oi = __shfl_up(bi2, off, 64);
            if (lane >= off && lane < IMGS - 64 && !(bv2 > ov)) { bv2 = ov; bi2 = oi; }
        }
        if (lane < IMGS - 64) {
            if (!(bv2 > tv)) { bv2 = tv; bi2 = ti; }
            kS[64 + lane] = bi2;
        }
    }
    __syncthreads();

    // 150 dot-tasks over 8 waves, protos in registers
    for (int r = 0; r < 19; ++r) {
        int task = r * 8 + wave;
        if (task < NTASK) {
            int row, sl;
            if (task < IMGS) {
                row = task;
                sl = msS[task / QUERY];
            } else {
                int m = task - IMGS;
                int kk = kS[m];
                int s2 = kk / N_WAY, c2 = kk - s2 * N_WAY;
                row = s2;
                sl = msS[c2];
            }
            const float2* q = (const float2*)(out_f +
                (size_t)(NS + j * IMGS + row) * ROWSZ + sl * DD) + lane * 5;
            float2 qv[5];
            #pragma unroll
            for (int k = 0; k < 5; ++k) qv[k] = q[k];
            float acc[N_WAY] = {0, 0, 0, 0, 0};
            #pragma unroll
            for (int n = 0; n < N_WAY; ++n) {
                #pragma unroll
                for (int k = 0; k < 5; ++k)
                    acc[n] += qv[k].x * pv[n][k].x + qv[k].y * pv[n][k].y;
            }
            #pragma unroll
            for (int n = 0; n < N_WAY; ++n) {
                #pragma unroll
                for (int off = 32; off; off >>= 1)
                    acc[n] += __shfl_down(acc[n], off, 64);
            }
            if (lane == 0) {
                #pragma unroll
                for (int n = 0; n < N_WAY; ++n) scS[task * N_WAY + n] = acc[n];
            }
        }
    }
    __syncthreads();

    // loss phase: threads 0..74, one element each
    float4 lv = make_float4(0.f, 0.f, 0.f, 0.f);
    if (t < IMGS) {
        int label = labels_query[j * IMGS + t];
        const float* sc1 = &scS[t * N_WAY];
        const float* sc2 = &scS[(IMGS + t) * N_WAY];
        // path 1: li_n = 2 q.p_n - ||p_n||^2 (||q||^2 cancels in log_softmax/argmax)
        {
            float li[N_WAY]; float mx = -3.0e38f;
            #pragma unroll
            for (int n = 0; n < N_WAY; ++n) { li[n] = 2.f * sc1[n] - p2S[n]; mx = fmaxf(mx, li[n]); }
            float se = 0.f;
            #pragma unroll
            for (int n = 0; n < N_WAY; ++n) se += expf(li[n] - mx);
            float lse = mx + logf(se);
            int bi = 0; float bv = li[0];
            #pragma unroll
            for (int n = 1; n < N_WAY; ++n) if (li[n] > bv) { bv = li[n]; bi = n; }
            lv.x = -(li[label] - lse);
            lv.z = (bi == label) ? 1.f : 0.f;
        }
        // path 2
        {
            float li[N_WAY]; float mx = -3.0e38f;
            #pragma unroll
            for (int n = 0; n < N_WAY; ++n) { li[n] = 2.f * sc2[n] - p2S[n]; mx = fmaxf(mx, li[n]); }
            float se = 0.f;
            #pragma unroll
            for (int n = 0; n < N_WAY; ++n) se += expf(li[n] - mx);
            float lse = mx + logf(se);
            int bi = 0; float bv = li[0];
            #pragma unroll
            for (int n = 1; n < N_WAY; ++n) if (li[n] > bv) { bv = li[n]; bi = n; }
            lv.y = -(li[label] - lse);
            lv.w = (bi == label) ? 1.f : 0.f;
        }
    }
    if (t < 128) redS[t] = lv;     // threads 75..127 write zeros
    __syncthreads();
    for (int w = 64; w; w >>= 1) {
        if (t < w) {
            redS[t].x += redS[t + w].x; redS[t].y += redS[t + w].y;
            redS[t].z += redS[t + w].z; redS[t].w += redS[t + w].w;
        }
        __syncthreads();
    }
    if (t == 0) part[j] = redS[0];
}

// ---------------- K3: final deterministic reduction (64 float4) ----------------
__global__ __launch_bounds__(64) void k_final(const float4* __restrict__ part,
                                              const float* __restrict__ att_loss,
                                              float* __restrict__ out) {
    int t = threadIdx.x;              // 64
    float4 v = part[t];
    #pragma unroll
    for (int off = 32; off; off >>= 1) {
        v.x += __shfl_down(v.x, off, 64);
        v.y += __shfl_down(v.y, off, 64);
        v.z += __shfl_down(v.z, off, 64);
        v.w += __shfl_down(v.w, off, 64);
    }
    if (t == 0) {
        out[0] = v.x / (float)NELEM + 0.1f * att_loss[0];
        out[1] = v.y / (float)NELEM;
        out[2] = v.z / (float)NELEM;
        out[3] = v.w / (float)NELEM;
    }
}

extern "C" void kernel_launch(void* const* d_in, const int* in_sizes, int n_in,
                              void* d_out, int out_size, void* d_ws, size_t ws_size,
                              hipStream_t stream) {
    const float* out_f        = (const float*)d_in[0];
    // d_in[1] = labels_support (unused by the reference's train path)
    const int*   labels_query = (const int*)d_in[2];
    const float* att_loss     = (const float*)d_in[3];
    float* out = (float*)d_out;

    // workspace layout
    float*  rowmean   = (float*)d_ws;                           // 51200 f
    float*  proto_all = rowmean + NROWS * NUM_SLOT;             // 320*8*640 f
    float*  pn2_all   = proto_all + NGROUP * NUM_SLOT * DD;     // 2560 f
    float4* part      = (float4*)(pn2_all + NGROUP * NUM_SLOT); // 64 float4

    k_pass1<<<NGROUP + NELEM, 256, 0, stream>>>(out_f, rowmean, proto_all, pn2_all);
    k_mega<<<BB, 512, 0, stream>>>(out_f, rowmean, proto_all, pn2_all,
                                   labels_query, part);
    k_final<<<1, 64, 0, stream>>>(part, att_loss, out);
}

// Round 9
// 40.863 us; speedup vs baseline: 1.2101x; 1.2101x over previous
//
#include <hip/hip_runtime.h>

// Problem constants (match reference)
#define BB 64
#define N_WAY 5
#define N_SHOT 5
#define QUERY 15
#define NUM_SLOT 8
#define DD 640
#define IMGS (N_WAY * QUERY)      // 75
#define NS (BB * N_WAY * N_SHOT)  // 1600 support rows
#define NROWS 6400                // total rows
#define ROWSZ (NUM_SLOT * DD)     // 5120 floats per row
#define F4_PER_SLOT 160           // 640/4
#define NELEM (BB * IMGS)         // 4800 loss elements
#define NGROUP (BB * N_WAY)       // 320 support groups
#define E_MAX 8                   // elements per mid block
#define PIECES 10                 // ceil(75/8)
#define NBLK (BB * PIECES)        // 640 mid blocks

// ---------------- K1: single streaming pass over out_f ----------------
// rowmean[6400][8] (per-row slot means), proto_all[320][8][640] (shot-means,
// all slots), pn2_all[320][8] (||proto||^2, all slots).
__global__ __launch_bounds__(256) void k_pass1(const float* __restrict__ out_f,
                                               float* __restrict__ rowmean,
                                               float* __restrict__ proto_all,
                                               float* __restrict__ pn2_all) {
    int b = blockIdx.x;
    int t = threadIdx.x;
    int slot = t >> 5;            // 0..7
    int l = t & 31;
    if (b < NGROUP) {
        const int g = b;          // support group j*5+c
        float4 acc[5];
        #pragma unroll
        for (int k = 0; k < 5; ++k) acc[k] = make_float4(0.f, 0.f, 0.f, 0.f);
        #pragma unroll
        for (int sh = 0; sh < N_SHOT; ++sh) {
            const float4* p = (const float4*)(out_f +
                ((size_t)((g * N_SHOT + sh) * NUM_SLOT + slot)) * DD);
            float s = 0.f;
            #pragma unroll
            for (int k = 0; k < 5; ++k) {
                float4 v = p[l + k * 32];
                acc[k].x += v.x; acc[k].y += v.y; acc[k].z += v.z; acc[k].w += v.w;
                s += (v.x + v.y) + (v.z + v.w);
            }
            #pragma unroll
            for (int off = 16; off; off >>= 1) s += __shfl_down(s, off, 32);
            if (l == 0) rowmean[(g * N_SHOT + sh) * NUM_SLOT + slot] = s * (1.f / DD);
        }
        float4* pp = (float4*)(proto_all + ((size_t)(g * NUM_SLOT + slot)) * DD);
        float ssq = 0.f;
        #pragma unroll
        for (int k = 0; k < 5; ++k) {
            acc[k].x *= 0.2f; acc[k].y *= 0.2f; acc[k].z *= 0.2f; acc[k].w *= 0.2f;
            pp[l + k * 32] = acc[k];
            ssq += acc[k].x * acc[k].x + acc[k].y * acc[k].y
                 + acc[k].z * acc[k].z + acc[k].w * acc[k].w;
        }
        #pragma unroll
        for (int off = 16; off; off >>= 1) ssq += __shfl_down(ssq, off, 32);
        if (l == 0) pn2_all[g * NUM_SLOT + slot] = ssq;
    } else {
        int r = NS + (b - NGROUP);   // query row
        const float4* p = (const float4*)(out_f + (size_t)r * ROWSZ) + slot * F4_PER_SLOT;
        float s = 0.f;
        #pragma unroll
        for (int k = 0; k < 5; ++k) {
            float4 v = p[l + k * 32];
            s += (v.x + v.y) + (v.z + v.w);
        }
        #pragma unroll
        for (int off = 16; off; off >>= 1) s += __shfl_down(s, off, 32);
        if (l == 0) rowmean[r * NUM_SLOT + slot] = s * (1.f / DD);
    }
}

// ---------------- K2: fused mid kernel, 10 blocks per batch, 8 elements each ----
// Per block: redundant cheap select + per-element argmax (no prefix scan),
// protos in registers, 4 score rounds, 8-thread softmax, one float4 partial.
__global__ __launch_bounds__(256) void k_mid(const float* __restrict__ out_f,
                                             const float* __restrict__ rowmean,
                                             const float* __restrict__ proto_all,
                                             const float* __restrict__ pn2_all,
                                             const int* __restrict__ labels_query,
                                             float4* __restrict__ part) {
    int b = blockIdx.x;            // j*PIECES + piece
    int j = b / PIECES, piece = b - j * PIECES;
    int m0 = piece * E_MAX;
    int E = IMGS - m0; if (E > E_MAX) E = E_MAX;
    int t = threadIdx.x;           // 256
    int wave = t >> 6, lane = t & 63;

    __shared__ __align__(16) float qb[IMGS * NUM_SLOT];  // 600 f
    __shared__ float supm[N_WAY * NUM_SLOT];             // 40 f
    __shared__ int   msS[N_WAY];
    __shared__ float p2S[N_WAY];
    __shared__ int   kkS[E_MAX];
    __shared__ float scS[2 * E_MAX * N_WAY];             // 80 f

    // stage query row-means (float4) + support slot-means
    const float* qbase = rowmean + (size_t)(NS + j * IMGS) * NUM_SLOT;
    if (t < 150) ((float4*)qb)[t] = ((const float4*)qbase)[t];
    if (t >= 160 && t < 160 + N_WAY * NUM_SLOT) {
        int idx = t - 160;
        int c = idx >> 3, s = idx & 7;
        const float* sb = rowmean + (size_t)j * (N_WAY * N_SHOT * NUM_SLOT)
                          + c * (N_SHOT * NUM_SLOT) + s;
        supm[idx] = (sb[0] + sb[8] + sb[16] + sb[24] + sb[32]) * 0.2f;
    }
    __syncthreads();

    // greedy cover select (serial, tiny; first-occurrence among untaken)
    if (t == 0) {
        unsigned taken = 0u;
        #pragma unroll
        for (int c = 0; c < N_WAY; ++c) {
            float best = -3.0e38f; int bi = 0;
            #pragma unroll
            for (int s = 0; s < NUM_SLOT; ++s) {
                float v = supm[c * NUM_SLOT + s];
                if (!((taken >> s) & 1u) && v > best) { best = v; bi = s; }
            }
            taken |= (1u << bi);
            msS[c] = bi;
        }
    }
    __syncthreads();

    // proto registers: pv[n][k] = float2 #(lane*5+k) of selected proto n
    float2 pv[N_WAY][5];
    #pragma unroll
    for (int n = 0; n < N_WAY; ++n) {
        const float2* pp = (const float2*)(proto_all +
            ((size_t)((j * N_WAY + n) * NUM_SLOT + msS[n])) * DD) + lane * 5;
        #pragma unroll
        for (int k = 0; k < 5; ++k) pv[n][k] = pp[k];
    }
    if (t < N_WAY) p2S[t] = pn2_all[(j * N_WAY + t) * NUM_SLOT + msS[t]];

    // per-element argmax over flat candidates l = s*5+c, s in [0, m]
    // (first occurrence == min flat index among strict maxima)
    for (int e = wave; e < E; e += 4) {
        int m = m0 + e;
        int cnt = (m + 1) * N_WAY;
        float v = -3.0e38f; int idx = 0x7fffffff;
        for (int li = lane; li < cnt; li += 64) {
            int s = li / N_WAY, c = li - s * N_WAY;
            float x = qb[s * NUM_SLOT + msS[c]];
            if (x > v) { v = x; idx = li; }   // ascending li + strict >
        }
        #pragma unroll
        for (int off = 32; off; off >>= 1) {
            float ov = __shfl_down(v, off, 64);
            int   oi = __shfl_down(idx, off, 64);
            if (ov > v || (ov == v && oi < idx)) { v = ov; idx = oi; }
        }
        if (lane == 0) kkS[e] = idx;
    }
    __syncthreads();

    // score rounds: 2E tasks (E path1 + E path2), one wave per task
    #pragma unroll
    for (int r = 0; r < 4; ++r) {
        int task = r * 4 + wave;
        if (task < 2 * E) {
            int row, sl;
            if (task < E) {
                int m = m0 + task;
                row = m;
                sl = msS[m / QUERY];
            } else {
                int kk = kkS[task - E];
                int s2 = kk / N_WAY, c2 = kk - s2 * N_WAY;
                row = s2;
                sl = msS[c2];
            }
            const float2* q = (const float2*)(out_f +
                (size_t)(NS + j * IMGS + row) * ROWSZ + sl * DD) + lane * 5;
            float2 qv[5];
            #pragma unroll
            for (int k = 0; k < 5; ++k) qv[k] = q[k];
            float acc[N_WAY] = {0, 0, 0, 0, 0};
            #pragma unroll
            for (int n = 0; n < N_WAY; ++n) {
                #pragma unroll
                for (int k = 0; k < 5; ++k)
                    acc[n] += qv[k].x * pv[n][k].x + qv[k].y * pv[n][k].y;
            }
            #pragma unroll
            for (int n = 0; n < N_WAY; ++n) {
                #pragma unroll
                for (int off = 32; off; off >>= 1)
                    acc[n] += __shfl_down(acc[n], off, 64);
            }
            if (lane == 0) {
                #pragma unroll
                for (int n = 0; n < N_WAY; ++n) scS[task * N_WAY + n] = acc[n];
            }
        }
    }
    __syncthreads();

    // loss phase: threads 0..E-1 (all in wave 0), one element each
    float4 lv = make_float4(0.f, 0.f, 0.f, 0.f);
    if (t < E) {
        int m = m0 + t;
        int label = labels_query[j * IMGS + m];
        const float* sc1 = &scS[t * N_WAY];
        const float* sc2 = &scS[(E + t) * N_WAY];
        // path 1: li_n = 2 q.p_n - ||p_n||^2 (||q||^2 cancels in log_softmax/argmax)
        {
            float li[N_WAY]; float mx = -3.0e38f;
            #pragma unroll
            for (int n = 0; n < N_WAY; ++n) { li[n] = 2.f * sc1[n] - p2S[n]; mx = fmaxf(mx, li[n]); }
            float se = 0.f;
            #pragma unroll
            for (int n = 0; n < N_WAY; ++n) se += expf(li[n] - mx);
            float lse = mx + logf(se);
            int bi = 0; float bv = li[0];
            #pragma unroll
            for (int n = 1; n < N_WAY; ++n) if (li[n] > bv) { bv = li[n]; bi = n; }
            lv.x = -(li[label] - lse);
            lv.z = (bi == label) ? 1.f : 0.f;
        }
        // path 2
        {
            float li[N_WAY]; float mx = -3.0e38f;
            #pragma unroll
            for (int n = 0; n < N_WAY; ++n) { li[n] = 2.f * sc2[n] - p2S[n]; mx = fmaxf(mx, li[n]); }
            float se = 0.f;
            #pragma unroll
            for (int n = 0; n < N_WAY; ++n) se += expf(li[n] - mx);
            float lse = mx + logf(se);
            int bi = 0; float bv = li[0];
            #pragma unroll
            for (int n = 1; n < N_WAY; ++n) if (li[n] > bv) { bv = li[n]; bi = n; }
            lv.y = -(li[label] - lse);
            lv.w = (bi == label) ? 1.f : 0.f;
        }
    }
    if (wave == 0) {
        // lanes >= E hold zeros; reduce lanes 0..7
        #pragma unroll
        for (int off = 4; off; off >>= 1) {
            lv.x += __shfl_down(lv.x, off, 64);
            lv.y += __shfl_down(lv.y, off, 64);
            lv.z += __shfl_down(lv.z, off, 64);
            lv.w += __shfl_down(lv.w, off, 64);
        }
        if (lane == 0) part[b] = lv;
    }
}

// ---------------- K3: final deterministic reduction (640 float4) ---------------
__global__ __launch_bounds__(256) void k_final(const float4* __restrict__ part,
                                               const float* __restrict__ att_loss,
                                               float* __restrict__ out) {
    __shared__ float4 red[256];
    int t = threadIdx.x;              // 256
    float4 s = make_float4(0.f, 0.f, 0.f, 0.f);
    for (int i = t; i < NBLK; i += 256) {
        float4 v = part[i];
        s.x += v.x; s.y += v.y; s.z += v.z; s.w += v.w;
    }
    red[t] = s;
    __syncthreads();
    for (int w = 128; w; w >>= 1) {
        if (t < w) {
            red[t].x += red[t + w].x; red[t].y += red[t + w].y;
            red[t].z += red[t + w].z; red[t].w += red[t + w].w;
        }
        __syncthreads();
    }
    if (t == 0) {
        out[0] = red[0].x / (float)NELEM + 0.1f * att_loss[0];
        out[1] = red[0].y / (float)NELEM;
        out[2] = red[0].z / (float)NELEM;
        out[3] = red[0].w / (float)NELEM;
    }
}

extern "C" void kernel_launch(void* const* d_in, const int* in_sizes, int n_in,
                              void* d_out, int out_size, void* d_ws, size_t ws_size,
                              hipStream_t stream) {
    const float* out_f        = (const float*)d_in[0];
    // d_in[1] = labels_support (unused by the reference's train path)
    const int*   labels_query = (const int*)d_in[2];
    const float* att_loss     = (const float*)d_in[3];
    float* out = (float*)d_out;

    // workspace layout
    float*  rowmean   = (float*)d_ws;                           // 51200 f
    float*  proto_all = rowmean + NROWS * NUM_SLOT;             // 320*8*640 f
    float*  pn2_all   = proto_all + NGROUP * NUM_SLOT * DD;     // 2560 f
    float4* part      = (float4*)(pn2_all + NGROUP * NUM_SLOT); // 640 float4

    k_pass1<<<NGROUP + NELEM, 256, 0, stream>>>(out_f, rowmean, proto_all, pn2_all);
    k_mid<<<NBLK, 256, 0, stream>>>(out_f, rowmean, proto_all, pn2_all,
                                    labels_query, part);
    k_final<<<1, 256, 0, stream>>>(part, att_loss, out);
}

// Round 10
// 39.155 us; speedup vs baseline: 1.2629x; 1.0436x over previous
//
#include <hip/hip_runtime.h>

// Problem constants (match reference)
#define BB 64
#define N_WAY 5
#define N_SHOT 5
#define QUERY 15
#define NUM_SLOT 8
#define DD 640
#define IMGS (N_WAY * QUERY)      // 75
#define NS (BB * N_WAY * N_SHOT)  // 1600 support rows
#define NROWS 6400                // total rows
#define ROWSZ (NUM_SLOT * DD)     // 5120 floats per row
#define F4_PER_SLOT 160           // 640/4
#define NELEM (BB * IMGS)         // 4800 loss elements
#define NGROUP (BB * N_WAY)       // 320 support groups
#define PIECES 19                 // ceil(75/4) pieces per batch
#define NBLK (BB * PIECES)        // 1216 mid blocks (4 elements each, 1/wave)

// ---------------- K1: single streaming pass over out_f ----------------
// rowmean[6400][8] (per-row slot means), proto_all[320][8][640] (shot-means,
// all slots), pn2_all[320][8] (||proto||^2, all slots).
__global__ __launch_bounds__(256) void k_pass1(const float* __restrict__ out_f,
                                               float* __restrict__ rowmean,
                                               float* __restrict__ proto_all,
                                               float* __restrict__ pn2_all) {
    int b = blockIdx.x;
    int t = threadIdx.x;
    int slot = t >> 5;            // 0..7
    int l = t & 31;
    if (b < NGROUP) {
        const int g = b;          // support group j*5+c
        float4 acc[5];
        #pragma unroll
        for (int k = 0; k < 5; ++k) acc[k] = make_float4(0.f, 0.f, 0.f, 0.f);
        #pragma unroll
        for (int sh = 0; sh < N_SHOT; ++sh) {
            const float4* p = (const float4*)(out_f +
                ((size_t)((g * N_SHOT + sh) * NUM_SLOT + slot)) * DD);
            float s = 0.f;
            #pragma unroll
            for (int k = 0; k < 5; ++k) {
                float4 v = p[l + k * 32];
                acc[k].x += v.x; acc[k].y += v.y; acc[k].z += v.z; acc[k].w += v.w;
                s += (v.x + v.y) + (v.z + v.w);
            }
            #pragma unroll
            for (int off = 16; off; off >>= 1) s += __shfl_down(s, off, 32);
            if (l == 0) rowmean[(g * N_SHOT + sh) * NUM_SLOT + slot] = s * (1.f / DD);
        }
        float4* pp = (float4*)(proto_all + ((size_t)(g * NUM_SLOT + slot)) * DD);
        float ssq = 0.f;
        #pragma unroll
        for (int k = 0; k < 5; ++k) {
            acc[k].x *= 0.2f; acc[k].y *= 0.2f; acc[k].z *= 0.2f; acc[k].w *= 0.2f;
            pp[l + k * 32] = acc[k];
            ssq += acc[k].x * acc[k].x + acc[k].y * acc[k].y
                 + acc[k].z * acc[k].z + acc[k].w * acc[k].w;
        }
        #pragma unroll
        for (int off = 16; off; off >>= 1) ssq += __shfl_down(ssq, off, 32);
        if (l == 0) pn2_all[g * NUM_SLOT + slot] = ssq;
    } else {
        int r = NS + (b - NGROUP);   // query row
        const float4* p = (const float4*)(out_f + (size_t)r * ROWSZ) + slot * F4_PER_SLOT;
        float s = 0.f;
        #pragma unroll
        for (int k = 0; k < 5; ++k) {
            float4 v = p[l + k * 32];
            s += (v.x + v.y) + (v.z + v.w);
        }
        #pragma unroll
        for (int off = 16; off; off >>= 1) s += __shfl_down(s, off, 32);
        if (l == 0) rowmean[r * NUM_SLOT + slot] = s * (1.f / DD);
    }
}

// ---------------- K2: fused mid kernel, one element per wave ----------------
// 19 blocks/batch x 4 waves = 76 wave-slots for 75 elements. Per block:
// cheap redundant setup (transposed qb + select), then fully independent
// per-wave work: argmax -> q loads -> dual dot -> reduce -> lane0 softmax.
__global__ __launch_bounds__(256) void k_mid(const float* __restrict__ out_f,
                                             const float* __restrict__ rowmean,
                                             const float* __restrict__ proto_all,
                                             const float* __restrict__ pn2_all,
                                             const int* __restrict__ labels_query,
                                             float4* __restrict__ part) {
    int b = blockIdx.x;            // j*PIECES + piece
    int j = b / PIECES, piece = b - j * PIECES;
    int t = threadIdx.x;           // 256
    int wave = t >> 6, lane = t & 63;
    int m = piece * 4 + wave;      // element this wave owns (>=75 -> idle)

    __shared__ float qbt[NUM_SLOT][76];      // transposed query rowmeans (pad 76)
    __shared__ float supm[N_WAY * NUM_SLOT];
    __shared__ int   msS[N_WAY];
    __shared__ float4 redS[4];

    // stage query row-means transposed (conflict-free argmax reads later)
    const float* qbase = rowmean + (size_t)(NS + j * IMGS) * NUM_SLOT;
    if (t < 150) {
        float4 v = ((const float4*)qbase)[t];
        int s = t >> 1, sl0 = (t & 1) * 4;
        qbt[sl0 + 0][s] = v.x; qbt[sl0 + 1][s] = v.y;
        qbt[sl0 + 2][s] = v.z; qbt[sl0 + 3][s] = v.w;
    }
    // support slot-means (threads 192..231)
    if (t >= 192 && t < 192 + N_WAY * NUM_SLOT) {
        int idx = t - 192;
        int c = idx >> 3, s = idx & 7;
        const float* sb = rowmean + (size_t)j * (N_WAY * N_SHOT * NUM_SLOT)
                          + c * (N_SHOT * NUM_SLOT) + s;
        supm[idx] = (sb[0] + sb[8] + sb[16] + sb[24] + sb[32]) * 0.2f;
    }
    __syncthreads();

    // greedy cover select (serial, tiny; first-occurrence among untaken)
    if (t == 0) {
        unsigned taken = 0u;
        #pragma unroll
        for (int c = 0; c < N_WAY; ++c) {
            float best = -3.0e38f; int bi = 0;
            #pragma unroll
            for (int s = 0; s < NUM_SLOT; ++s) {
                float v = supm[c * NUM_SLOT + s];
                if (!((taken >> s) & 1u) && v > best) { best = v; bi = s; }
            }
            taken |= (1u << bi);
            msS[c] = bi;
        }
    }
    __syncthreads();

    int ms[N_WAY];
    #pragma unroll
    for (int n = 0; n < N_WAY; ++n) ms[n] = msS[n];

    // per-lane registers: selected protos (float2 slice) + ||p||^2 (broadcast)
    float2 pv[N_WAY][5];
    float p2r[N_WAY];
    #pragma unroll
    for (int n = 0; n < N_WAY; ++n) {
        const float2* pp = (const float2*)(proto_all +
            ((size_t)((j * N_WAY + n) * NUM_SLOT + ms[n])) * DD) + lane * 5;
        #pragma unroll
        for (int k = 0; k < 5; ++k) pv[n][k] = pp[k];
        p2r[n] = pn2_all[(j * N_WAY + n) * NUM_SLOT + ms[n]];
    }

    float4 lv = make_float4(0.f, 0.f, 0.f, 0.f);
    if (m < IMGS) {
        // issue q1 load early (row m, its class's selected slot)
        const float2* q1p = (const float2*)(out_f +
            (size_t)(NS + j * IMGS + m) * ROWSZ + ms[m / QUERY] * DD) + lane * 5;
        float2 q1v[5];
        #pragma unroll
        for (int k = 0; k < 5; ++k) q1v[k] = q1p[k];

        // argmax over flat candidates l = s*5+c, s in [0, m]
        // (first occurrence == max value, min flat index among ties)
        float bv = -3.0e38f; int bi = 0x7fffffff;
        #pragma unroll
        for (int rep = 0; rep < 2; ++rep) {
            int s = lane + rep * 64;
            if (s <= m) {
                #pragma unroll
                for (int c = 0; c < N_WAY; ++c) {
                    float x = qbt[ms[c]][s];          // consecutive -> conflict-free
                    int flat = s * N_WAY + c;
                    if (x > bv || (x == bv && flat < bi)) { bv = x; bi = flat; }
                }
            }
        }
        #pragma unroll
        for (int off = 32; off; off >>= 1) {
            float ov = __shfl_down(bv, off, 64);
            int   oi = __shfl_down(bi, off, 64);
            if (ov > bv || (ov == bv && oi < bi)) { bv = ov; bi = oi; }
        }
        bi = __shfl(bi, 0, 64);                       // broadcast winner

        int s2 = bi / N_WAY, c2 = bi - s2 * N_WAY;
        const float2* q2p = (const float2*)(out_f +
            (size_t)(NS + j * IMGS + s2) * ROWSZ + ms[c2] * DD) + lane * 5;
        float2 q2v[5];
        #pragma unroll
        for (int k = 0; k < 5; ++k) q2v[k] = q2p[k];

        float s1[N_WAY] = {0, 0, 0, 0, 0};
        float s2a[N_WAY] = {0, 0, 0, 0, 0};
        #pragma unroll
        for (int n = 0; n < N_WAY; ++n) {
            #pragma unroll
            for (int k = 0; k < 5; ++k) {
                s1[n]  += q1v[k].x * pv[n][k].x + q1v[k].y * pv[n][k].y;
                s2a[n] += q2v[k].x * pv[n][k].x + q2v[k].y * pv[n][k].y;
            }
        }
        #pragma unroll
        for (int n = 0; n < N_WAY; ++n) {
            #pragma unroll
            for (int off = 32; off; off >>= 1) {
                s1[n]  += __shfl_down(s1[n],  off, 64);
                s2a[n] += __shfl_down(s2a[n], off, 64);
            }
        }
        if (lane == 0) {
            int label = labels_query[j * IMGS + m];
            // path 1: li_n = 2 q.p_n - ||p_n||^2 (||q||^2 cancels)
            {
                float li[N_WAY]; float mx = -3.0e38f;
                #pragma unroll
                for (int n = 0; n < N_WAY; ++n) { li[n] = 2.f * s1[n] - p2r[n]; mx = fmaxf(mx, li[n]); }
                float se = 0.f;
                #pragma unroll
                for (int n = 0; n < N_WAY; ++n) se += expf(li[n] - mx);
                float lse = mx + logf(se);
                int bn = 0; float bvv = li[0];
                #pragma unroll
                for (int n = 1; n < N_WAY; ++n) if (li[n] > bvv) { bvv = li[n]; bn = n; }
                lv.x = -(li[label] - lse);
                lv.z = (bn == label) ? 1.f : 0.f;
            }
            // path 2
            {
                float li[N_WAY]; float mx = -3.0e38f;
                #pragma unroll
                for (int n = 0; n < N_WAY; ++n) { li[n] = 2.f * s2a[n] - p2r[n]; mx = fmaxf(mx, li[n]); }
                float se = 0.f;
                #pragma unroll
                for (int n = 0; n < N_WAY; ++n) se += expf(li[n] - mx);
                float lse = mx + logf(se);
                int bn = 0; float bvv = li[0];
                #pragma unroll
                for (int n = 1; n < N_WAY; ++n) if (li[n] > bvv) { bvv = li[n]; bn = n; }
                lv.y = -(li[label] - lse);
                lv.w = (bn == label) ? 1.f : 0.f;
            }
        }
    }
    if (lane == 0) redS[wave] = lv;        // idle waves write zeros
    __syncthreads();
    if (t == 0) {
        float4 s0 = redS[0], s1 = redS[1], s2 = redS[2], s3 = redS[3];
        part[b] = make_float4(s0.x + s1.x + s2.x + s3.x,
                              s0.y + s1.y + s2.y + s3.y,
                              s0.z + s1.z + s2.z + s3.z,
                              s0.w + s1.w + s2.w + s3.w);
    }
}

// ---------------- K3: final deterministic reduction (1216 float4) --------------
__global__ __launch_bounds__(256) void k_final(const float4* __restrict__ part,
                                               const float* __restrict__ att_loss,
                                               float* __restrict__ out) {
    __shared__ float4 red[256];
    int t = threadIdx.x;              // 256
    float4 s = make_float4(0.f, 0.f, 0.f, 0.f);
    for (int i = t; i < NBLK; i += 256) {
        float4 v = part[i];
        s.x += v.x; s.y += v.y; s.z += v.z; s.w += v.w;
    }
    red[t] = s;
    __syncthreads();
    for (int w = 128; w; w >>= 1) {
        if (t < w) {
            red[t].x += red[t + w].x; red[t].y += red[t + w].y;
            red[t].z += red[t + w].z; red[t].w += red[t + w].w;
        }
        __syncthreads();
    }
    if (t == 0) {
        out[0] = red[0].x / (float)NELEM + 0.1f * att_loss[0];
        out[1] = red[0].y / (float)NELEM;
        out[2] = red[0].z / (float)NELEM;
        out[3] = red[0].w / (float)NELEM;
    }
}

extern "C" void kernel_launch(void* const* d_in, const int* in_sizes, int n_in,
                              void* d_out, int out_size, void* d_ws, size_t ws_size,
                              hipStream_t stream) {
    const float* out_f        = (const float*)d_in[0];
    // d_in[1] = labels_support (unused by the reference's train path)
    const int*   labels_query = (const int*)d_in[2];
    const float* att_loss     = (const float*)d_in[3];
    float* out = (float*)d_out;

    // workspace layout
    float*  rowmean   = (float*)d_ws;                           // 51200 f
    float*  proto_all = rowmean + NROWS * NUM_SLOT;             // 320*8*640 f
    float*  pn2_all   = proto_all + NGROUP * NUM_SLOT * DD;     // 2560 f
    float4* part      = (float4*)(pn2_all + NGROUP * NUM_SLOT); // 1216 float4

    k_pass1<<<NGROUP + NELEM, 256, 0, stream>>>(out_f, rowmean, proto_all, pn2_all);
    k_mid<<<NBLK, 256, 0, stream>>>(out_f, rowmean, proto_all, pn2_all,
                                    labels_query, part);
    k_final<<<1, 256, 0, stream>>>(part, att_loss, out);
}